// Round 1
// baseline (114.542 us; speedup 1.0000x reference)
//
#include <hip/hip_runtime.h>
#include <math.h>

#define BLK 256
#define ROWF 7
#define TILE_F (BLK * ROWF)      // 1792 floats staged per array per block
#define TILE_V4 (TILE_F / 4)     // 448 float4s (block base is 16B-aligned: 7168*bid)

// ---------------------------------------------------------------------------
// Rotated-box intersection area via Green's theorem (no polygon clipping):
// area(P∩Q) = 1/2 ∮ (x dy − y dx) = Σ P-edge pieces clipped to Q's AAB frame
// + Σ Q-edge pieces clipped to P's AAB frame + 1/2·cross(t, R·ΣΔ) translation
// correction (x dy − y dx is rotation-invariant).  Each piece is a branchless
// Liang-Barsky slab clip; empty clips give exactly-zero-length pieces.
//
// Memory structure (this revision): the 5-of-7-float strided reads of
// box_preds / reg_targets (28B stride, 4B-aligned rows -> scalar dword loads
// only, ~28 cache-line transactions per wave load) are replaced by
// block-cooperative float4 LDS staging: 448 coalesced 16B loads per array per
// block. Per-thread rows are then read from LDS (stride-7 words: lanes t and
// t+32 alias one bank = free 2-way). Pair-1 operands are read from LDS after
// pair-0 is done -> lower peak VGPR. Anchors stay as direct loads (reused for
// both batches; issued first so latency hides under staging).
// ---------------------------------------------------------------------------

__device__ __forceinline__ float clamp_mag(float x) {
    return copysignf(fmaxf(fabsf(x), 1e-30f), x);
}

// clip segment p + s*e, s in [0,1], to box [-hx,hx] x [-hy,hy]; r = 1/e (pre-clamped)
__device__ __forceinline__ void edge_piece(float px, float py, float ex, float ey,
                                           float rx, float ry, float hx, float hy,
                                           float& area2, float& Dx, float& Dy)
{
    float sx0 = (-hx - px) * rx, sx1 = (hx - px) * rx;
    float sy0 = (-hy - py) * ry, sy1 = (hy - py) * ry;
    float smin = fmaxf(fmaxf(fminf(sx0, sx1), fminf(sy0, sy1)), 0.0f);
    float smax = fminf(fminf(fmaxf(sx0, sx1), fmaxf(sy0, sy1)), 1.0f);
    smax = fmaxf(smax, smin);                  // empty -> zero-length at smin
    float ax = fmaf(smin, ex, px), ay = fmaf(smin, ey, py);
    float bx = fmaf(smax, ex, px), by = fmaf(smax, ey, py);
    float ux = bx - ax, uy = by - ay;          // exactly 0 when smin==smax
    area2 += fmaf(ax, uy, -(ay * ux));         // cross(a, b-a) == cross(a,b)
    Dx += ux; Dy += uy;
}

// Full pair IoU -> loss for one (pred, target) box pair sharing an anchor.
__device__ __forceinline__ float pair_loss(const float bp[5], const float rt[5],
                                           float xa, float ya, float dxa, float dya,
                                           float ra, float diag,
                                           float ip, int oh, float w)
{
    // decode P (pred) / Q (target): fields {x, y, dx, dy, r}
    float x1  = fmaf(bp[0], diag, xa);
    float y1  = fmaf(bp[1], diag, ya);
    float dx1 = __expf(bp[2]) * dxa;
    float dy1 = __expf(bp[3]) * dya;
    float r1  = bp[4] + ra;

    float x2  = fmaf(rt[0], diag, xa);
    float y2  = fmaf(rt[1], diag, ya);
    float dx2 = __expf(rt[2]) * dxa;
    float dy2 = __expf(rt[3]) * dya;
    float r2  = rt[4] + ra;

    float a1 = dx1 * dy1, a2 = dx2 * dy2;
    float h1x = 0.5f * dx1, h1y = 0.5f * dy1;
    float h2x = 0.5f * dx2, h2y = 0.5f * dy2;

    // P in Q's frame: p_Q = R(dr)·p_P + t
    float c2v = __cosf(r2), s2v = __sinf(r2);
    float dr  = r1 - r2;
    float cd  = __cosf(dr), sd = __sinf(dr);
    float ddx = x1 - x2, ddy = y1 - y2;
    float tx  = fmaf(c2v, ddx,  s2v * ddy);
    float ty  = fmaf(-s2v, ddx, c2v * ddy);

    // P half-edge vectors in Q frame
    float ux_ = h1x * cd,  uy_ = h1x * sd;
    float vx_ = -h1y * sd, vy_ = h1y * cd;
    // full edge vectors ±2u, ±2v and their shared reciprocals
    float eux = 2.0f * ux_, euy = 2.0f * uy_;
    float evx = 2.0f * vx_, evy = 2.0f * vy_;
    float ruxP = __fdividef(1.0f, clamp_mag(eux));
    float ruyP = __fdividef(1.0f, clamp_mag(euy));
    float rvxP = __fdividef(1.0f, clamp_mag(evx));
    float rvyP = __fdividef(1.0f, clamp_mag(evy));
    // corners (CCW)
    float p0x = tx + ux_ + vx_, p0y = ty + uy_ + vy_;
    float p1x = tx - ux_ + vx_, p1y = ty - uy_ + vy_;
    float p2x = tx - ux_ - vx_, p2y = ty - uy_ - vy_;
    float p3x = tx + ux_ - vx_, p3y = ty + uy_ - vy_;

    float area2 = 0.0f, dDx = 0.0f, dDy = 0.0f;
    edge_piece(p0x, p0y, -eux, -euy, -ruxP, -ruyP, h2x, h2y, area2, dDx, dDy);
    edge_piece(p1x, p1y, -evx, -evy, -rvxP, -rvyP, h2x, h2y, area2, dDx, dDy);
    edge_piece(p2x, p2y,  eux,  euy,  ruxP,  ruyP, h2x, h2y, area2, dDx, dDy);
    edge_piece(p3x, p3y,  evx,  evy,  rvxP,  rvyP, h2x, h2y, area2, dDx, dDy);

    // Q in P's frame: u' = R^T·(h2x,0), v' = R^T·(0,h2y), o = -R^T·t
    float upx = h2x * cd,  upy = -h2x * sd;
    float vpx = h2y * sd,  vpy = h2y * cd;
    float ox  = -(fmaf(cd, tx,  sd * ty));
    float oy  = -(fmaf(-sd, tx, cd * ty));
    float equx = 2.0f * upx, equy = 2.0f * upy;
    float eqvx = 2.0f * vpx, eqvy = 2.0f * vpy;
    float ruxQ = __fdividef(1.0f, clamp_mag(equx));
    float ruyQ = __fdividef(1.0f, clamp_mag(equy));
    float rvxQ = __fdividef(1.0f, clamp_mag(eqvx));
    float rvyQ = __fdividef(1.0f, clamp_mag(eqvy));
    float q0x = ox + upx + vpx, q0y = oy + upy + vpy;
    float q1x = ox - upx + vpx, q1y = oy - upy + vpy;
    float q2x = ox - upx - vpx, q2y = oy - upy - vpy;
    float q3x = ox + upx - vpx, q3y = oy + upy - vpy;

    float Dx = 0.0f, Dy = 0.0f;
    edge_piece(q0x, q0y, -equx, -equy, -ruxQ, -ruyQ, h1x, h1y, area2, Dx, Dy);
    edge_piece(q1x, q1y, -eqvx, -eqvy, -rvxQ, -rvyQ, h1x, h1y, area2, Dx, Dy);
    edge_piece(q2x, q2y,  equx,  equy,  ruxQ,  ruyQ, h1x, h1y, area2, Dx, Dy);
    edge_piece(q3x, q3y,  eqvx,  eqvy,  rvxQ,  rvyQ, h1x, h1y, area2, Dx, Dy);

    // translation correction: cross(t, R·D)
    float RDx = fmaf(cd, Dx, -(sd * Dy));
    float RDy = fmaf(sd, Dx,   cd * Dy);
    area2 += fmaf(tx, RDy, -(ty * RDx));

    float inter = 0.5f * fabsf(area2);
    float uni = fmaxf(a1 + a2 - inter, 1e-6f);
    float iou = __fdividef(inter, uni);

    float target = (oh > 0) ? iou : 0.0f;
    float z  = __fdividef(1.0f, 1.0f + __expf(-ip));   // sigmoid
    float pt = __logf(1.0f + __expf(z)) - z * target;  // logaddexp(0,z) - z*target
    return pt * w;
}

__global__ __launch_bounds__(BLK)
void iou_pred_loss_kernel(const float* __restrict__ iou_preds,
                          const int*   __restrict__ one_hot,
                          const float* __restrict__ weights,
                          const float* __restrict__ anchors,
                          const float* __restrict__ box_preds,
                          const float* __restrict__ reg_targets,
                          float* __restrict__ out,
                          int N, int B)
{
    __shared__ float s_bp0[TILE_F];
    __shared__ float s_rt0[TILE_F];
    __shared__ float s_bp1[TILE_F];
    __shared__ float s_rt1[TILE_F];

    int tid   = threadIdx.x;
    int row0  = blockIdx.x * BLK;
    int n_idx = row0 + tid;
    bool valid = (n_idx < N);

    int yspan = gridDim.y;                 // = ceil(B/2)
    int b0 = blockIdx.y;
    int b1 = blockIdx.y + yspan;
    bool has2 = (b1 < B);
    size_t g0 = (size_t)b0 * N + (valid ? n_idx : (N - 1));
    size_t g1 = (size_t)(has2 ? b1 : b0) * N + (valid ? n_idx : (N - 1));

    // ---- anchors: 5 direct loads, issued first (reused for both batches;
    //      latency hides under the staging loads below) ----
    const float* an = anchors + (size_t)(valid ? n_idx : (N - 1)) * ROWF;
    float xa = an[0], ya = an[1], dxa = an[3], dya = an[4], ra = an[6];

    // ---- per-element scalars: already perfectly coalesced, keep direct ----
    float ip0 = iou_preds[g0], ip1 = iou_preds[g1];
    int   oh0 = one_hot[g0],   oh1 = one_hot[g1];
    float w0  = weights[g0],   w1  = weights[g1];

    // ---- cooperative float4 staging of the four strided 7-float arrays ----
    size_t base0 = ((size_t)b0 * N + row0) * ROWF;                    // 16B-aligned
    size_t base1 = ((size_t)(has2 ? b1 : b0) * N + row0) * ROWF;      // 16B-aligned
    int rows = N - row0; if (rows > BLK) rows = BLK;

    if (rows == BLK) {
        const float4* gb0 = (const float4*)(box_preds   + base0);
        const float4* gr0 = (const float4*)(reg_targets + base0);
        const float4* gb1 = (const float4*)(box_preds   + base1);
        const float4* gr1 = (const float4*)(reg_targets + base1);
        float4* sb0 = (float4*)s_bp0;
        float4* sr0 = (float4*)s_rt0;
        float4* sb1 = (float4*)s_bp1;
        float4* sr1 = (float4*)s_rt1;
        sb0[tid] = gb0[tid];
        sr0[tid] = gr0[tid];
        sb1[tid] = gb1[tid];
        sr1[tid] = gr1[tid];
        if (tid < TILE_V4 - BLK) {                 // 448 - 256 = 192 extras
            sb0[tid + BLK] = gb0[tid + BLK];
            sr0[tid + BLK] = gr0[tid + BLK];
            sb1[tid + BLK] = gb1[tid + BLK];
            sr1[tid + BLK] = gr1[tid + BLK];
        }
    } else {
        // tail block (not hit for N % 256 == 0): scalar guarded copy
        int cnt = rows * ROWF;
        const float* gb0 = box_preds   + base0;
        const float* gr0 = reg_targets + base0;
        const float* gb1 = box_preds   + base1;
        const float* gr1 = reg_targets + base1;
        for (int i = tid; i < cnt; i += BLK) {
            s_bp0[i] = gb0[i];
            s_rt0[i] = gr0[i];
            s_bp1[i] = gb1[i];
            s_rt1[i] = gr1[i];
        }
    }
    __syncthreads();

    float diag = sqrtf(fmaf(dxa, dxa, dya * dya));
    int lb = tid * ROWF;   // stride-7 word addressing: lanes t / t+32 alias one
                           // bank -> 2-way access, free on gfx950 (m136)

    // ---- pair 0 ----
    {
        float bp[5] = { s_bp0[lb + 0], s_bp0[lb + 1], s_bp0[lb + 3],
                        s_bp0[lb + 4], s_bp0[lb + 6] };
        float rt[5] = { s_rt0[lb + 0], s_rt0[lb + 1], s_rt0[lb + 3],
                        s_rt0[lb + 4], s_rt0[lb + 6] };
        float r = pair_loss(bp, rt, xa, ya, dxa, dya, ra, diag, ip0, oh0, w0);
        if (valid) out[g0] = r;
    }

    // ---- pair 1 (operands pulled from LDS only now -> lower peak VGPR) ----
    if (has2) {
        float bp[5] = { s_bp1[lb + 0], s_bp1[lb + 1], s_bp1[lb + 3],
                        s_bp1[lb + 4], s_bp1[lb + 6] };
        float rt[5] = { s_rt1[lb + 0], s_rt1[lb + 1], s_rt1[lb + 3],
                        s_rt1[lb + 4], s_rt1[lb + 6] };
        float r = pair_loss(bp, rt, xa, ya, dxa, dya, ra, diag, ip1, oh1, w1);
        if (valid) out[g1] = r;
    }
}

extern "C" void kernel_launch(void* const* d_in, const int* in_sizes, int n_in,
                              void* d_out, int out_size, void* d_ws, size_t ws_size,
                              hipStream_t stream) {
    const float* iou_preds   = (const float*)d_in[0];
    const int*   one_hot     = (const int*)  d_in[1];
    const float* weights     = (const float*)d_in[2];
    const float* anchors     = (const float*)d_in[3];
    const float* box_preds   = (const float*)d_in[4];
    const float* reg_targets = (const float*)d_in[5];
    float* out = (float*)d_out;

    int total = in_sizes[0];       // B*N
    int N     = in_sizes[3] / 7;   // anchor count
    int B     = total / N;

    dim3 grid((N + BLK - 1) / BLK, (B + 1) / 2);
    iou_pred_loss_kernel<<<grid, dim3(BLK), 0, stream>>>(
        iou_preds, one_hot, weights, anchors, box_preds, reg_targets,
        out, N, B);
}